// Round 1
// baseline (412.041 us; speedup 1.0000x reference)
//
#include <hip/hip_runtime.h>
#include <math.h>

// FCNNSlopeValuationFunction: per-row angle -> zone -> gather dir[row, zone],
// masked by z_1[:,0] != 0.
//
// Numerics notes (must match the harness's numpy-f32 reference bit-for-bit at
// truncation boundaries):
//  - atan2 computed in double then rounded to float == correctly-rounded f32
//    atan2 (matches modern glibc atan2f; near-identical to 1-ulp libms).
//  - degrees = single f32 multiply by f32(180/pi), NO fma contraction
//    (pragma below), matching numpy's npy_rad2degf.
//  - (90+int(phi))%360, ((pcs+11)/22) floor, %8: exact for these small ints.

__global__ __launch_bounds__(256) void slope_zone_kernel(
    const float* __restrict__ z1,
    const float* __restrict__ dir,
    float* __restrict__ out,
    int n)
{
#pragma clang fp contract(off)
    int i = blockIdx.x * blockDim.x + threadIdx.x;
    if (i >= n) return;

    // z_1 row: 16 floats, 64B-aligned. Need cols 0..4.
    const float4* zrow = reinterpret_cast<const float4*>(z1 + (size_t)i * 16);
    float4 a = zrow[0];                       // x=line, y=lx, z=ly, w=rx
    float ry = z1[(size_t)i * 16 + 4];

    float dx = a.w - a.y;                     // rx - lx   (f32, matches ref)
    float dy = -(ry - a.z);                   // -(ry - ly) incl. signed-zero

    // correctly-rounded f32 atan2 via double
    float phi_rad = (float)atan2((double)dy, (double)dx);
    // numpy degrees: single f32 multiply by f32-rounded 180/pi
    float phi = phi_rad * 57.29577951308232f;
    if (phi < 0.0f) phi = 360.0f + phi;       // f32 add, matches ref

    int t = (int)phi;                         // trunc == floor (phi >= 0)
    int pcs = (90 + t) % 360;                 // t in [0,360] -> pcs in [0,359]
    // ((pcs + 11.0) // 22.0) % 8  — exact in f32 for these integers
    int z = (int)(((float)pcs + 11.0f) / 22.0f);
    int zone = z & 7;                         // z in [0,16], nonneg -> %8

    float picked = dir[(size_t)i * 8 + zone];
    out[i] = (a.x != 0.0f) ? picked : 0.0f;
}

extern "C" void kernel_launch(void* const* d_in, const int* in_sizes, int n_in,
                              void* d_out, int out_size, void* d_ws, size_t ws_size,
                              hipStream_t stream) {
    const float* z1  = (const float*)d_in[0];   // (B,16) f32
    const float* dir = (const float*)d_in[1];   // (B,8)  f32
    float* out = (float*)d_out;                 // (B,)   f32
    int n = out_size;
    int threads = 256;
    int blocks = (n + threads - 1) / threads;
    hipLaunchKernelGGL(slope_zone_kernel, dim3(blocks), dim3(threads), 0, stream,
                       z1, dir, out, n);
}